// Round 1
// baseline (1698.138 us; speedup 1.0000x reference)
//
#include <hip/hip_runtime.h>

#define NN 50000
#define NE 800000

__device__ __forceinline__ float sigm(float v) { return 1.0f / (1.0f + __expf(-v)); }

// ---------------------------------------------------------------------------
// Per-node precompute: G[n][k][o] = sum_i x[n][i] * eW2[k][i*16+o]
//                      xb[n][o]   = sum_i x[n][i] * eb2[i*16+o]
// One thread per (n, k, o-quad): 50000*64 threads.
// ---------------------------------------------------------------------------
template<int DIN>
__global__ void precompute_G(const float* __restrict__ x,
                             const float* __restrict__ eW2,   // [16][DIN*16]
                             const float* __restrict__ eb2,   // [DIN*16]
                             float* __restrict__ G,           // [NN][16][16]
                             float* __restrict__ xb)          // [NN][16]
{
    int t = blockIdx.x * blockDim.x + threadIdx.x;
    if (t >= NN * 64) return;
    int n  = t >> 6;
    int r  = t & 63;
    int k  = r >> 2;
    int ob = r & 3;
    float xi[DIN];
#pragma unroll
    for (int i = 0; i < DIN; ++i) xi[i] = x[n * DIN + i];
    float ax = 0.f, ay = 0.f, az = 0.f, aw = 0.f;
#pragma unroll
    for (int i = 0; i < DIN; ++i) {
        const float* w = eW2 + (k * DIN + i) * 16 + ob * 4;
        ax += xi[i] * w[0]; ay += xi[i] * w[1]; az += xi[i] * w[2]; aw += xi[i] * w[3];
    }
    ((float4*)G)[n * 64 + k * 4 + ob] = make_float4(ax, ay, az, aw);
    if (k == 0) {
        float bx = 0.f, by = 0.f, bz = 0.f, bw = 0.f;
#pragma unroll
        for (int i = 0; i < DIN; ++i) {
            const float* bb = eb2 + i * 16 + ob * 4;
            bx += xi[i] * bb[0]; by += xi[i] * bb[1]; bz += xi[i] * bb[2]; bw += xi[i] * bb[3];
        }
        ((float4*)xb)[n * 4 + ob] = make_float4(bx, by, bz, bw);
    }
}

// ---------------------------------------------------------------------------
// Edge pass (G-factored): h = silu(ea@eW1+eb1);
// msg[o] = xb[src][o] + sum_k h[k]*G[src][k][o]; atomic scatter to agg[dst].
// One thread per edge.
// ---------------------------------------------------------------------------
template<bool COUNT>
__global__ void edge_pass_G(const int* __restrict__ ei,
                            const float* __restrict__ ea,    // [NE][4]
                            const float* __restrict__ eW1,   // [4][16]
                            const float* __restrict__ eb1,   // [16]
                            const float* __restrict__ G,     // [NN][16][16]
                            const float* __restrict__ xb,    // [NN][16]
                            float* __restrict__ agg,         // [NN][16]
                            float* __restrict__ cnt)         // [NN]
{
    __shared__ __align__(16) float w1[64];
    __shared__ __align__(16) float b1[16];
    int tid = threadIdx.x;
    if (tid < 64) w1[tid] = eW1[tid];
    if (tid < 16) b1[tid] = eb1[tid];
    __syncthreads();
    int e = blockIdx.x * blockDim.x + tid;
    if (e >= NE) return;
    int src = ei[e];
    int dst = ei[NE + e];
    float4 a = ((const float4*)ea)[e];
    float h[16];
#pragma unroll
    for (int j = 0; j < 16; ++j) {
        float p = b1[j] + a.x * w1[j] + a.y * w1[16 + j] + a.z * w1[32 + j] + a.w * w1[48 + j];
        h[j] = p * sigm(p);
    }
    const float4* G4  = (const float4*)G  + (size_t)src * 64;
    const float4* xb4 = (const float4*)xb + (size_t)src * 4;
#pragma unroll
    for (int ob = 0; ob < 4; ++ob) {
        float4 acc = xb4[ob];
#pragma unroll
        for (int k = 0; k < 16; ++k) {
            float4 g = G4[k * 4 + ob];
            acc.x += h[k] * g.x; acc.y += h[k] * g.y; acc.z += h[k] * g.z; acc.w += h[k] * g.w;
        }
        float* ad = agg + dst * 16 + ob * 4;
        unsafeAtomicAdd(ad + 0, acc.x);
        unsafeAtomicAdd(ad + 1, acc.y);
        unsafeAtomicAdd(ad + 2, acc.z);
        unsafeAtomicAdd(ad + 3, acc.w);
    }
    if (COUNT) unsafeAtomicAdd(cnt + dst, 1.0f);
}

// ---------------------------------------------------------------------------
// Edge pass (direct, small-ws fallback): all edge-MLP weights in LDS.
// ---------------------------------------------------------------------------
template<int DIN, bool COUNT>
__global__ void edge_pass_direct(const int* __restrict__ ei,
                                 const float* __restrict__ ea,
                                 const float* __restrict__ eW1,
                                 const float* __restrict__ eb1,
                                 const float* __restrict__ eW2,  // [16][DIN*16]
                                 const float* __restrict__ eb2,  // [DIN*16]
                                 const float* __restrict__ xin,  // [NN][DIN]
                                 float* __restrict__ agg,
                                 float* __restrict__ cnt)
{
    __shared__ __align__(16) float w1[64];
    __shared__ __align__(16) float b1[16];
    __shared__ __align__(16) float w2[16 * DIN * 16];
    __shared__ __align__(16) float b2[DIN * 16];
    int tid = threadIdx.x;
    if (tid < 64) w1[tid] = eW1[tid];
    if (tid < 16) b1[tid] = eb1[tid];
    for (int i = tid; i < 16 * DIN * 16; i += blockDim.x) w2[i] = eW2[i];
    for (int i = tid; i < DIN * 16; i += blockDim.x) b2[i] = eb2[i];
    __syncthreads();
    int e = blockIdx.x * blockDim.x + tid;
    if (e >= NE) return;
    int src = ei[e];
    int dst = ei[NE + e];
    float4 a = ((const float4*)ea)[e];
    float h[16];
#pragma unroll
    for (int j = 0; j < 16; ++j) {
        float p = b1[j] + a.x * w1[j] + a.y * w1[16 + j] + a.z * w1[32 + j] + a.w * w1[48 + j];
        h[j] = p * sigm(p);
    }
    float xs[DIN];
#pragma unroll
    for (int i = 0; i < DIN; ++i) xs[i] = xin[(size_t)src * DIN + i];
#pragma unroll 1
    for (int ob = 0; ob < 4; ++ob) {
        float ax = 0.f, ay = 0.f, az = 0.f, aw = 0.f;
#pragma unroll
        for (int i = 0; i < DIN; ++i) {
            const float4* bv = (const float4*)(b2 + i * 16) + ob;
            float4 w = *bv;
#pragma unroll
            for (int k = 0; k < 16; ++k) {
                const float4* wv = (const float4*)(w2 + (k * DIN + i) * 16) + ob;
                float4 g = *wv;
                w.x += h[k] * g.x; w.y += h[k] * g.y; w.z += h[k] * g.z; w.w += h[k] * g.w;
            }
            ax += xs[i] * w.x; ay += xs[i] * w.y; az += xs[i] * w.z; aw += xs[i] * w.w;
        }
        float* ad = agg + dst * 16 + ob * 4;
        unsafeAtomicAdd(ad + 0, ax);
        unsafeAtomicAdd(ad + 1, ay);
        unsafeAtomicAdd(ad + 2, az);
        unsafeAtomicAdd(ad + 3, aw);
    }
    if (COUNT) unsafeAtomicAdd(cnt + dst, 1.0f);
}

// ---------------------------------------------------------------------------
// Node update: xout = relu(xin @ root + agg/max(cnt,1) + bias)
// ---------------------------------------------------------------------------
template<int DIN>
__global__ void node_update(const float* __restrict__ xin,
                            const float* __restrict__ root,  // [DIN][16]
                            const float* __restrict__ bias,  // [16]
                            const float* __restrict__ agg,
                            const float* __restrict__ cnt,
                            float* __restrict__ xout)        // [NN][16]
{
    __shared__ __align__(16) float rt[DIN * 16];
    __shared__ __align__(16) float bs[16];
    int tid = threadIdx.x;
    for (int i = tid; i < DIN * 16; i += blockDim.x) rt[i] = root[i];
    if (tid < 16) bs[tid] = bias[tid];
    __syncthreads();
    int n = blockIdx.x * blockDim.x + tid;
    if (n >= NN) return;
    float xs[DIN];
#pragma unroll
    for (int i = 0; i < DIN; ++i) xs[i] = xin[(size_t)n * DIN + i];
    float inv = 1.0f / fmaxf(cnt[n], 1.0f);
#pragma unroll
    for (int ob = 0; ob < 4; ++ob) {
        float4 s = ((const float4*)(agg + (size_t)n * 16))[ob];
        float4 b = ((const float4*)bs)[ob];
        s.x = s.x * inv + b.x; s.y = s.y * inv + b.y;
        s.z = s.z * inv + b.z; s.w = s.w * inv + b.w;
#pragma unroll
        for (int i = 0; i < DIN; ++i) {
            float4 r = ((const float4*)(rt + i * 16))[ob];
            s.x += xs[i] * r.x; s.y += xs[i] * r.y; s.z += xs[i] * r.z; s.w += xs[i] * r.w;
        }
        s.x = fmaxf(s.x, 0.f); s.y = fmaxf(s.y, 0.f);
        s.z = fmaxf(s.z, 0.f); s.w = fmaxf(s.w, 0.f);
        ((float4*)(xout + (size_t)n * 16))[ob] = s;
    }
}

// ---------------------------------------------------------------------------
// Final node kernel: x2 = relu(x1@root1 + agg/cnt + bias1);
// out = sigmoid(silu(x2@mW1+mb1)@mW2+mb2)
// ---------------------------------------------------------------------------
__global__ void node_final(const float* __restrict__ x1,
                           const float* __restrict__ root,   // [16][16]
                           const float* __restrict__ bias,   // [16]
                           const float* __restrict__ agg,
                           const float* __restrict__ cnt,
                           const float* __restrict__ mW1,    // [16][16]
                           const float* __restrict__ mb1,    // [16]
                           const float* __restrict__ mW2,    // [16][1]
                           const float* __restrict__ mb2,    // [1]
                           float* __restrict__ out)          // [NN]
{
    __shared__ __align__(16) float rt[256];
    __shared__ __align__(16) float w1m[256];
    __shared__ __align__(16) float bs[16];
    __shared__ __align__(16) float b1m[16];
    __shared__ __align__(16) float w2m[16];
    __shared__ float b2m;
    int tid = threadIdx.x;
    for (int i = tid; i < 256; i += blockDim.x) { rt[i] = root[i]; w1m[i] = mW1[i]; }
    if (tid < 16) { bs[tid] = bias[tid]; b1m[tid] = mb1[tid]; w2m[tid] = mW2[tid]; }
    if (tid == 0) b2m = mb2[0];
    __syncthreads();
    int n = blockIdx.x * blockDim.x + tid;
    if (n >= NN) return;
    float xs[16];
#pragma unroll
    for (int i = 0; i < 16; ++i) xs[i] = x1[(size_t)n * 16 + i];
    float inv = 1.0f / fmaxf(cnt[n], 1.0f);
    float x2[16];
#pragma unroll
    for (int o = 0; o < 16; ++o) {
        float s = agg[(size_t)n * 16 + o] * inv + bs[o];
#pragma unroll
        for (int i = 0; i < 16; ++i) s += xs[i] * rt[i * 16 + o];
        x2[o] = fmaxf(s, 0.f);
    }
    float z = b2m;
#pragma unroll
    for (int j = 0; j < 16; ++j) {
        float p = b1m[j];
#pragma unroll
        for (int o = 0; o < 16; ++o) p += x2[o] * w1m[o * 16 + j];
        z += (p * sigm(p)) * w2m[j];
    }
    out[n] = sigm(z);
}

// ---------------------------------------------------------------------------
// Host launch
// ---------------------------------------------------------------------------
extern "C" void kernel_launch(void* const* d_in, const int* in_sizes, int n_in,
                              void* d_out, int out_size, void* d_ws, size_t ws_size,
                              hipStream_t stream) {
    const float* x     = (const float*)d_in[0];
    const int*   ei    = (const int*)  d_in[1];
    const float* ea    = (const float*)d_in[2];
    const float* eW1_0 = (const float*)d_in[3];
    const float* eb1_0 = (const float*)d_in[4];
    const float* eW2_0 = (const float*)d_in[5];
    const float* eb2_0 = (const float*)d_in[6];
    const float* root0 = (const float*)d_in[7];
    const float* bias0 = (const float*)d_in[8];
    const float* eW1_1 = (const float*)d_in[9];
    const float* eb1_1 = (const float*)d_in[10];
    const float* eW2_1 = (const float*)d_in[11];
    const float* eb2_1 = (const float*)d_in[12];
    const float* root1 = (const float*)d_in[13];
    const float* bias1 = (const float*)d_in[14];
    const float* mW1   = (const float*)d_in[15];
    const float* mb1   = (const float*)d_in[16];
    const float* mW2   = (const float*)d_in[17];
    const float* mb2   = (const float*)d_in[18];
    float* out = (float*)d_out;

    float* ws  = (float*)d_ws;
    float* agg = ws;                  // [NN*16]  = 800000 floats
    float* cnt = ws + 800000;         // [NN]     = 50000 floats
    float* x1  = ws + 850000;         // [NN*16]  = 800000 floats
    float* xb  = ws + 1650000;        // [NN*16]  = 800000 floats
    float* G   = ws + 2450000;        // [NN*256] = 12800000 floats
    const size_t needG = (size_t)(2450000 + 12800000) * sizeof(float); // 61 MB
    bool useG = ws_size >= needG;

    // zero agg + cnt (contiguous region at start of ws)
    hipMemsetAsync(agg, 0, 850000 * sizeof(float), stream);

    const int EB = 256, EG = (NE + EB - 1) / EB;          // 3125
    const int PB = 256, PG = (NN * 64 + PB - 1) / PB;     // 12500
    const int NB = 256, NG = (NN + NB - 1) / NB;          // 196

    // ---- layer 0 ----
    if (useG) {
        precompute_G<8><<<PG, PB, 0, stream>>>(x, eW2_0, eb2_0, G, xb);
        edge_pass_G<true><<<EG, EB, 0, stream>>>(ei, ea, eW1_0, eb1_0, G, xb, agg, cnt);
    } else {
        edge_pass_direct<8, true><<<EG, EB, 0, stream>>>(ei, ea, eW1_0, eb1_0, eW2_0, eb2_0, x, agg, cnt);
    }
    node_update<8><<<NG, NB, 0, stream>>>(x, root0, bias0, agg, cnt, x1);

    // ---- layer 1 ----
    hipMemsetAsync(agg, 0, 800000 * sizeof(float), stream);
    if (useG) {
        precompute_G<16><<<PG, PB, 0, stream>>>(x1, eW2_1, eb2_1, G, xb);
        edge_pass_G<false><<<EG, EB, 0, stream>>>(ei, ea, eW1_1, eb1_1, G, xb, agg, cnt);
    } else {
        edge_pass_direct<16, false><<<EG, EB, 0, stream>>>(ei, ea, eW1_1, eb1_1, eW2_1, eb2_1, x1, agg, cnt);
    }
    node_final<<<NG, NB, 0, stream>>>(x1, root1, bias1, agg, cnt, mW1, mb1, mW2, mb2, out);
}

// Round 2
// 1493.211 us; speedup vs baseline: 1.1372x; 1.1372x over previous
//
#include <hip/hip_runtime.h>

#define NN 50000
#define NE 800000

__device__ __forceinline__ float sigm(float v) { return 1.0f / (1.0f + __expf(-v)); }

// ---------------------------------------------------------------------------
// Fused edge pass (direct): h = silu(ea@eW1+eb1);
// Wedge[i][o] = eb2[i*16+o] + sum_k h[k]*eW2[k][i*16+o]  (weights in LDS,
// wave-uniform broadcast reads); msg[o] = sum_i x[src][i]*Wedge[i][o];
// atomic scatter-add to agg[dst] (+count on layer 0).
// One thread per edge.
// ---------------------------------------------------------------------------
template<int DIN, bool COUNT>
__global__ void edge_fused(const int* __restrict__ ei,
                           const float* __restrict__ ea,    // [NE][4]
                           const float* __restrict__ eW1,   // [4][16]
                           const float* __restrict__ eb1,   // [16]
                           const float* __restrict__ eW2,   // [16][DIN*16]
                           const float* __restrict__ eb2,   // [DIN*16]
                           const float* __restrict__ xin,   // [NN][DIN]
                           float* __restrict__ agg,         // [NN][16]
                           float* __restrict__ cnt)         // [NN]
{
    __shared__ __align__(16) float w1[64];
    __shared__ __align__(16) float b1[16];
    __shared__ __align__(16) float w2[16 * DIN * 16];
    __shared__ __align__(16) float b2[DIN * 16];
    int tid = threadIdx.x;
    if (tid < 64) w1[tid] = eW1[tid];
    if (tid < 16) b1[tid] = eb1[tid];
    for (int i = tid; i < 16 * DIN * 16; i += blockDim.x) w2[i] = eW2[i];
    for (int i = tid; i < DIN * 16; i += blockDim.x) b2[i] = eb2[i];
    __syncthreads();

    int e = blockIdx.x * blockDim.x + tid;
    if (e >= NE) return;
    int src = ei[e];
    int dst = ei[NE + e];
    float4 a = ((const float4*)ea)[e];

    // edge MLP hidden: h[16]
    float h[16];
#pragma unroll
    for (int j = 0; j < 16; ++j) {
        float p = b1[j] + a.x * w1[j] + a.y * w1[16 + j] + a.z * w1[32 + j] + a.w * w1[48 + j];
        h[j] = p * sigm(p);
    }

    // gather source features (L2-resident: x table is 1.6-3.2 MB)
    float xs[DIN];
#pragma unroll
    for (int i4 = 0; i4 < DIN / 4; ++i4)
        ((float4*)xs)[i4] = ((const float4*)(xin + (size_t)src * DIN))[i4];

    // msg[o] = sum_i xs[i] * (b2[i][o] + sum_k h[k]*w2[k][i][o])
#pragma unroll 1
    for (int ob = 0; ob < 4; ++ob) {
        float4 acc = make_float4(0.f, 0.f, 0.f, 0.f);
#pragma unroll
        for (int i = 0; i < DIN; ++i) {
            float4 w = *((const float4*)(b2 + i * 16) + ob);
#pragma unroll
            for (int k = 0; k < 16; ++k) {
                float4 g = *((const float4*)(w2 + (k * DIN + i) * 16) + ob);
                w.x += h[k] * g.x; w.y += h[k] * g.y;
                w.z += h[k] * g.z; w.w += h[k] * g.w;
            }
            acc.x += xs[i] * w.x; acc.y += xs[i] * w.y;
            acc.z += xs[i] * w.z; acc.w += xs[i] * w.w;
        }
        float* ad = agg + (size_t)dst * 16 + ob * 4;
        unsafeAtomicAdd(ad + 0, acc.x);
        unsafeAtomicAdd(ad + 1, acc.y);
        unsafeAtomicAdd(ad + 2, acc.z);
        unsafeAtomicAdd(ad + 3, acc.w);
    }
    if (COUNT) unsafeAtomicAdd(cnt + dst, 1.0f);
}

// ---------------------------------------------------------------------------
// Node update: xout = relu(xin @ root + agg/max(cnt,1) + bias)
// ---------------------------------------------------------------------------
template<int DIN>
__global__ void node_update(const float* __restrict__ xin,
                            const float* __restrict__ root,  // [DIN][16]
                            const float* __restrict__ bias,  // [16]
                            const float* __restrict__ agg,
                            const float* __restrict__ cnt,
                            float* __restrict__ xout)        // [NN][16]
{
    __shared__ __align__(16) float rt[DIN * 16];
    __shared__ __align__(16) float bs[16];
    int tid = threadIdx.x;
    for (int i = tid; i < DIN * 16; i += blockDim.x) rt[i] = root[i];
    if (tid < 16) bs[tid] = bias[tid];
    __syncthreads();
    int n = blockIdx.x * blockDim.x + tid;
    if (n >= NN) return;
    float xs[DIN];
#pragma unroll
    for (int i = 0; i < DIN; ++i) xs[i] = xin[(size_t)n * DIN + i];
    float inv = 1.0f / fmaxf(cnt[n], 1.0f);
#pragma unroll
    for (int ob = 0; ob < 4; ++ob) {
        float4 s = ((const float4*)(agg + (size_t)n * 16))[ob];
        float4 b = ((const float4*)bs)[ob];
        s.x = s.x * inv + b.x; s.y = s.y * inv + b.y;
        s.z = s.z * inv + b.z; s.w = s.w * inv + b.w;
#pragma unroll
        for (int i = 0; i < DIN; ++i) {
            float4 r = ((const float4*)(rt + i * 16))[ob];
            s.x += xs[i] * r.x; s.y += xs[i] * r.y; s.z += xs[i] * r.z; s.w += xs[i] * r.w;
        }
        s.x = fmaxf(s.x, 0.f); s.y = fmaxf(s.y, 0.f);
        s.z = fmaxf(s.z, 0.f); s.w = fmaxf(s.w, 0.f);
        ((float4*)(xout + (size_t)n * 16))[ob] = s;
    }
}

// ---------------------------------------------------------------------------
// Final node kernel: x2 = relu(x1@root1 + agg/cnt + bias1);
// out = sigmoid(silu(x2@mW1+mb1)@mW2+mb2)
// ---------------------------------------------------------------------------
__global__ void node_final(const float* __restrict__ x1,
                           const float* __restrict__ root,   // [16][16]
                           const float* __restrict__ bias,   // [16]
                           const float* __restrict__ agg,
                           const float* __restrict__ cnt,
                           const float* __restrict__ mW1,    // [16][16]
                           const float* __restrict__ mb1,    // [16]
                           const float* __restrict__ mW2,    // [16][1]
                           const float* __restrict__ mb2,    // [1]
                           float* __restrict__ out)          // [NN]
{
    __shared__ __align__(16) float rt[256];
    __shared__ __align__(16) float w1m[256];
    __shared__ __align__(16) float bs[16];
    __shared__ __align__(16) float b1m[16];
    __shared__ __align__(16) float w2m[16];
    __shared__ float b2m;
    int tid = threadIdx.x;
    for (int i = tid; i < 256; i += blockDim.x) { rt[i] = root[i]; w1m[i] = mW1[i]; }
    if (tid < 16) { bs[tid] = bias[tid]; b1m[tid] = mb1[tid]; w2m[tid] = mW2[tid]; }
    if (tid == 0) b2m = mb2[0];
    __syncthreads();
    int n = blockIdx.x * blockDim.x + tid;
    if (n >= NN) return;
    float xs[16];
#pragma unroll
    for (int i = 0; i < 16; ++i) xs[i] = x1[(size_t)n * 16 + i];
    float inv = 1.0f / fmaxf(cnt[n], 1.0f);
    float x2[16];
#pragma unroll
    for (int o = 0; o < 16; ++o) {
        float s = agg[(size_t)n * 16 + o] * inv + bs[o];
#pragma unroll
        for (int i = 0; i < 16; ++i) s += xs[i] * rt[i * 16 + o];
        x2[o] = fmaxf(s, 0.f);
    }
    float z = b2m;
#pragma unroll
    for (int j = 0; j < 16; ++j) {
        float p = b1m[j];
#pragma unroll
        for (int o = 0; o < 16; ++o) p += x2[o] * w1m[o * 16 + j];
        z += (p * sigm(p)) * w2m[j];
    }
    out[n] = sigm(z);
}

// ---------------------------------------------------------------------------
// Host launch
// ---------------------------------------------------------------------------
extern "C" void kernel_launch(void* const* d_in, const int* in_sizes, int n_in,
                              void* d_out, int out_size, void* d_ws, size_t ws_size,
                              hipStream_t stream) {
    const float* x     = (const float*)d_in[0];
    const int*   ei    = (const int*)  d_in[1];
    const float* ea    = (const float*)d_in[2];
    const float* eW1_0 = (const float*)d_in[3];
    const float* eb1_0 = (const float*)d_in[4];
    const float* eW2_0 = (const float*)d_in[5];
    const float* eb2_0 = (const float*)d_in[6];
    const float* root0 = (const float*)d_in[7];
    const float* bias0 = (const float*)d_in[8];
    const float* eW1_1 = (const float*)d_in[9];
    const float* eb1_1 = (const float*)d_in[10];
    const float* eW2_1 = (const float*)d_in[11];
    const float* eb2_1 = (const float*)d_in[12];
    const float* root1 = (const float*)d_in[13];
    const float* bias1 = (const float*)d_in[14];
    const float* mW1   = (const float*)d_in[15];
    const float* mb1   = (const float*)d_in[16];
    const float* mW2   = (const float*)d_in[17];
    const float* mb2   = (const float*)d_in[18];
    float* out = (float*)d_out;

    float* ws  = (float*)d_ws;
    float* agg = ws;                  // [NN*16]  = 800000 floats
    float* cnt = ws + 800000;         // [NN]     = 50000 floats
    float* x1  = ws + 850000;         // [NN*16]  = 800000 floats

    // zero agg + cnt (contiguous region at start of ws)
    hipMemsetAsync(agg, 0, 850000 * sizeof(float), stream);

    const int EB = 256, EG = (NE + EB - 1) / EB;          // 3125
    const int NB = 256, NG = (NN + NB - 1) / NB;          // 196

    // ---- layer 0 ----
    edge_fused<8, true><<<EG, EB, 0, stream>>>(ei, ea, eW1_0, eb1_0, eW2_0, eb2_0, x, agg, cnt);
    node_update<8><<<NG, NB, 0, stream>>>(x, root0, bias0, agg, cnt, x1);

    // ---- layer 1 ----
    hipMemsetAsync(agg, 0, 800000 * sizeof(float), stream);
    edge_fused<16, false><<<EG, EB, 0, stream>>>(ei, ea, eW1_1, eb1_1, eW2_1, eb2_1, x1, agg, cnt);
    node_final<<<NG, NB, 0, stream>>>(x1, root1, bias1, agg, cnt, mW1, mb1, mW2, mb2, out);
}

// Round 3
// 941.873 us; speedup vs baseline: 1.8029x; 1.5854x over previous
//
#include <hip/hip_runtime.h>

#define NN 50000
#define NE 800000

__device__ __forceinline__ float sigm(float v) { return 1.0f / (1.0f + __expf(-v)); }

// ---------------------------------------------------------------------------
// Fused edge pass: h = silu(ea@eW1+eb1);
// Wedge[i][o] = eb2[i*16+o] + sum_k h[k]*eW2[k][i*16+o]  (weights in LDS,
// wave-uniform broadcast reads); msg[o] = sum_i x[src][i]*Wedge[i][o].
// Then LDS-stage msg + dst and remap lanes so the atomic scatter issues
// 16 contiguous channels per edge from contiguous lanes: each atomic
// wave-instr covers 4 complete 64B agg rows instead of 64 scattered 4B ops.
// One thread per edge; NE = 3125 * 256 exactly (no tail).
// ---------------------------------------------------------------------------
template<int DIN, bool COUNT>
__global__ void edge_fused(const int* __restrict__ ei,
                           const float* __restrict__ ea,    // [NE][4]
                           const float* __restrict__ eW1,   // [4][16]
                           const float* __restrict__ eb1,   // [16]
                           const float* __restrict__ eW2,   // [16][DIN*16]
                           const float* __restrict__ eb2,   // [DIN*16]
                           const float* __restrict__ xin,   // [NN][DIN]
                           float* __restrict__ agg,         // [NN][16] (64B rows)
                           float* __restrict__ cnt)         // [NN]
{
    constexpr int MROW = 260;                 // 256 + 4 pad (bank-conflict-free both phases)
    __shared__ __align__(16) float w1[64];
    __shared__ __align__(16) float b1[16];
    __shared__ __align__(16) float w2[16 * DIN * 16];
    __shared__ __align__(16) float b2[DIN * 16];
    __shared__ float smemM[16 * MROW];
    __shared__ int   sdst[256];
    int tid = threadIdx.x;
    if (tid < 64) w1[tid] = eW1[tid];
    if (tid < 16) b1[tid] = eb1[tid];
    for (int i = tid; i < 16 * DIN * 16; i += blockDim.x) w2[i] = eW2[i];
    for (int i = tid; i < DIN * 16; i += blockDim.x) b2[i] = eb2[i];
    __syncthreads();

    int e = blockIdx.x * 256 + tid;
    int src = ei[e];
    int dst = ei[NE + e];
    float4 a = ((const float4*)ea)[e];

    // edge MLP hidden: h[16]
    float h[16];
#pragma unroll
    for (int j = 0; j < 16; ++j) {
        float p = b1[j] + a.x * w1[j] + a.y * w1[16 + j] + a.z * w1[32 + j] + a.w * w1[48 + j];
        h[j] = p * sigm(p);
    }

    // gather source features (x table is 1.6-3.2 MB, L2-resident)
    float xs[DIN];
#pragma unroll
    for (int i4 = 0; i4 < DIN / 4; ++i4)
        ((float4*)xs)[i4] = ((const float4*)(xin + (size_t)src * DIN))[i4];

    // msg[o] = sum_i xs[i] * (b2[i][o] + sum_k h[k]*w2[k][i][o])
    float msg[16];
#pragma unroll 1
    for (int ob = 0; ob < 4; ++ob) {
        float4 acc = make_float4(0.f, 0.f, 0.f, 0.f);
#pragma unroll
        for (int i = 0; i < DIN; ++i) {
            float4 w = *((const float4*)(b2 + i * 16) + ob);
#pragma unroll
            for (int k = 0; k < 16; ++k) {
                float4 g = *((const float4*)(w2 + (k * DIN + i) * 16) + ob);
                w.x += h[k] * g.x; w.y += h[k] * g.y;
                w.z += h[k] * g.z; w.w += h[k] * g.w;
            }
            acc.x += xs[i] * w.x; acc.y += xs[i] * w.y;
            acc.z += xs[i] * w.z; acc.w += xs[i] * w.w;
        }
        msg[ob * 4 + 0] = acc.x; msg[ob * 4 + 1] = acc.y;
        msg[ob * 4 + 2] = acc.z; msg[ob * 4 + 3] = acc.w;
    }

    // stage: channel-major, stride-1 across tid -> conflict-free writes
    sdst[tid] = dst;
#pragma unroll
    for (int ch = 0; ch < 16; ++ch) smemM[ch * MROW + tid] = msg[ch];
    if (COUNT) unsafeAtomicAdd(cnt + dst, 1.0f);
    __syncthreads();

    // scatter: round r, thread t -> edge r*16 + (t>>4), channel t&15.
    // 16 contiguous lanes hit one complete 64B agg row per edge.
#pragma unroll
    for (int r = 0; r < 16; ++r) {
        int le = r * 16 + (tid >> 4);
        int ch = tid & 15;
        float v = smemM[ch * MROW + le];   // 2 lanes/bank: free
        int d = sdst[le];                  // 16-lane broadcast: free
        unsafeAtomicAdd(agg + (size_t)d * 16 + ch, v);
    }
}

// ---------------------------------------------------------------------------
// Node update: xout = relu(xin @ root + agg/max(cnt,1) + bias)
// ---------------------------------------------------------------------------
template<int DIN>
__global__ void node_update(const float* __restrict__ xin,
                            const float* __restrict__ root,  // [DIN][16]
                            const float* __restrict__ bias,  // [16]
                            const float* __restrict__ agg,
                            const float* __restrict__ cnt,
                            float* __restrict__ xout)        // [NN][16]
{
    __shared__ __align__(16) float rt[DIN * 16];
    __shared__ __align__(16) float bs[16];
    int tid = threadIdx.x;
    for (int i = tid; i < DIN * 16; i += blockDim.x) rt[i] = root[i];
    if (tid < 16) bs[tid] = bias[tid];
    __syncthreads();
    int n = blockIdx.x * blockDim.x + tid;
    if (n >= NN) return;
    float xs[DIN];
#pragma unroll
    for (int i = 0; i < DIN; ++i) xs[i] = xin[(size_t)n * DIN + i];
    float inv = 1.0f / fmaxf(cnt[n], 1.0f);
#pragma unroll
    for (int ob = 0; ob < 4; ++ob) {
        float4 s = ((const float4*)(agg + (size_t)n * 16))[ob];
        float4 b = ((const float4*)bs)[ob];
        s.x = s.x * inv + b.x; s.y = s.y * inv + b.y;
        s.z = s.z * inv + b.z; s.w = s.w * inv + b.w;
#pragma unroll
        for (int i = 0; i < DIN; ++i) {
            float4 r = ((const float4*)(rt + i * 16))[ob];
            s.x += xs[i] * r.x; s.y += xs[i] * r.y; s.z += xs[i] * r.z; s.w += xs[i] * r.w;
        }
        s.x = fmaxf(s.x, 0.f); s.y = fmaxf(s.y, 0.f);
        s.z = fmaxf(s.z, 0.f); s.w = fmaxf(s.w, 0.f);
        ((float4*)(xout + (size_t)n * 16))[ob] = s;
    }
}

// ---------------------------------------------------------------------------
// Final node kernel: x2 = relu(x1@root1 + agg/cnt + bias1);
// out = sigmoid(silu(x2@mW1+mb1)@mW2+mb2)
// ---------------------------------------------------------------------------
__global__ void node_final(const float* __restrict__ x1,
                           const float* __restrict__ root,   // [16][16]
                           const float* __restrict__ bias,   // [16]
                           const float* __restrict__ agg,
                           const float* __restrict__ cnt,
                           const float* __restrict__ mW1,    // [16][16]
                           const float* __restrict__ mb1,    // [16]
                           const float* __restrict__ mW2,    // [16][1]
                           const float* __restrict__ mb2,    // [1]
                           float* __restrict__ out)          // [NN]
{
    __shared__ __align__(16) float rt[256];
    __shared__ __align__(16) float w1m[256];
    __shared__ __align__(16) float bs[16];
    __shared__ __align__(16) float b1m[16];
    __shared__ __align__(16) float w2m[16];
    __shared__ float b2m;
    int tid = threadIdx.x;
    for (int i = tid; i < 256; i += blockDim.x) { rt[i] = root[i]; w1m[i] = mW1[i]; }
    if (tid < 16) { bs[tid] = bias[tid]; b1m[tid] = mb1[tid]; w2m[tid] = mW2[tid]; }
    if (tid == 0) b2m = mb2[0];
    __syncthreads();
    int n = blockIdx.x * blockDim.x + tid;
    if (n >= NN) return;
    float xs[16];
#pragma unroll
    for (int i = 0; i < 16; ++i) xs[i] = x1[(size_t)n * 16 + i];
    float inv = 1.0f / fmaxf(cnt[n], 1.0f);
    float x2[16];
#pragma unroll
    for (int o = 0; o < 16; ++o) {
        float s = agg[(size_t)n * 16 + o] * inv + bs[o];
#pragma unroll
        for (int i = 0; i < 16; ++i) s += xs[i] * rt[i * 16 + o];
        x2[o] = fmaxf(s, 0.f);
    }
    float z = b2m;
#pragma unroll
    for (int j = 0; j < 16; ++j) {
        float p = b1m[j];
#pragma unroll
        for (int o = 0; o < 16; ++o) p += x2[o] * w1m[o * 16 + j];
        z += (p * sigm(p)) * w2m[j];
    }
    out[n] = sigm(z);
}

// ---------------------------------------------------------------------------
// Host launch
// ---------------------------------------------------------------------------
extern "C" void kernel_launch(void* const* d_in, const int* in_sizes, int n_in,
                              void* d_out, int out_size, void* d_ws, size_t ws_size,
                              hipStream_t stream) {
    const float* x     = (const float*)d_in[0];
    const int*   ei    = (const int*)  d_in[1];
    const float* ea    = (const float*)d_in[2];
    const float* eW1_0 = (const float*)d_in[3];
    const float* eb1_0 = (const float*)d_in[4];
    const float* eW2_0 = (const float*)d_in[5];
    const float* eb2_0 = (const float*)d_in[6];
    const float* root0 = (const float*)d_in[7];
    const float* bias0 = (const float*)d_in[8];
    const float* eW1_1 = (const float*)d_in[9];
    const float* eb1_1 = (const float*)d_in[10];
    const float* eW2_1 = (const float*)d_in[11];
    const float* eb2_1 = (const float*)d_in[12];
    const float* root1 = (const float*)d_in[13];
    const float* bias1 = (const float*)d_in[14];
    const float* mW1   = (const float*)d_in[15];
    const float* mb1   = (const float*)d_in[16];
    const float* mW2   = (const float*)d_in[17];
    const float* mb2   = (const float*)d_in[18];
    float* out = (float*)d_out;

    float* ws  = (float*)d_ws;
    float* agg = ws;                  // [NN*16]  = 800000 floats (64B rows)
    float* cnt = ws + 800000;         // [NN]     = 50000 floats
    float* x1  = ws + 850000;         // [NN*16]  = 800000 floats

    // zero agg + cnt (contiguous region at start of ws)
    hipMemsetAsync(agg, 0, 850000 * sizeof(float), stream);

    const int EB = 256, EG = NE / EB;                     // 3125 exact
    const int NB = 256, NG = (NN + NB - 1) / NB;          // 196

    // ---- layer 0 ----
    edge_fused<8, true><<<EG, EB, 0, stream>>>(ei, ea, eW1_0, eb1_0, eW2_0, eb2_0, x, agg, cnt);
    node_update<8><<<NG, NB, 0, stream>>>(x, root0, bias0, agg, cnt, x1);

    // ---- layer 1 ----
    hipMemsetAsync(agg, 0, 800000 * sizeof(float), stream);
    edge_fused<16, false><<<EG, EB, 0, stream>>>(ei, ea, eW1_1, eb1_1, eW2_1, eb2_1, x1, agg, cnt);
    node_final<<<NG, NB, 0, stream>>>(x1, root1, bias1, agg, cnt, mW1, mb1, mW2, mb2, out);
}

// Round 4
// 924.350 us; speedup vs baseline: 1.8371x; 1.0190x over previous
//
#include <hip/hip_runtime.h>

#define NN 50000
#define NE 800000
#define CAP 96   // bucket capacity; max degree for Poisson(16) over 50k nodes is ~45

__device__ __forceinline__ float sigm(float v) { return 1.0f / (1.0f + __expf(-v)); }

// ---------------------------------------------------------------------------
// Build dst-indexed adjacency buckets: cnt_i[d] = degree, elist[d*CAP + j] = edge id.
// 800k int atomics on a 200 KB L2-resident counter table. Runs ONCE per launch,
// reused by both layers (graph is static).
// ---------------------------------------------------------------------------
__global__ void build_buckets(const int* __restrict__ ei,
                              int* __restrict__ cnt_i,
                              int* __restrict__ elist)
{
    int e = blockIdx.x * 256 + threadIdx.x;     // NE == 3125*256 exactly
    int d = ei[NE + e];
    int pos = atomicAdd(cnt_i + d, 1);
    if (pos < CAP) elist[(size_t)d * CAP + pos] = e;
}

// ---------------------------------------------------------------------------
// Fused per-node gather + NNConv + node update (+ output MLP when FINAL).
// 16-lane group per node, lane ch = output channel. Per incident edge:
//   h[ch] = silu(eb1[ch] + ea . eW1[:,ch])                  (4 FMA + shfl-shared)
//   msg[ch] = sum_i xs[i]*b2[i][ch] + sum_k h[k]*(sum_i xs[i]*w2[k][i][ch])
// w2 in LDS as [k][ch][i] -> per-lane contiguous float4 reads; the 4 groups of
// a wave read identical addresses (broadcast, conflict-free).
// acc[ch] stays in a register; NO atomics anywhere in the fp path.
// ---------------------------------------------------------------------------
template<int DIN, bool FINAL>
__global__ __launch_bounds__(256) void node_gather(
        const int*   __restrict__ ei,
        const float* __restrict__ ea,     // [NE][4]
        const float* __restrict__ eW1,    // [4][16]
        const float* __restrict__ eb1,    // [16]
        const float* __restrict__ eW2,    // [16][DIN*16]
        const float* __restrict__ eb2,    // [DIN*16]
        const float* __restrict__ root,   // [DIN][16]
        const float* __restrict__ bias,   // [16]
        const float* __restrict__ xin,    // [NN][DIN]
        const int*   __restrict__ cnt_i,
        const int*   __restrict__ elist,
        const float* __restrict__ mW1,    // [16][16]  (FINAL only)
        const float* __restrict__ mb1,    // [16]
        const float* __restrict__ mW2,    // [16]
        const float* __restrict__ mb2,    // [1]
        float* __restrict__ xout)         // [NN][16] or [NN] (FINAL)
{
    __shared__ __align__(16) float w1[64];
    __shared__ __align__(16) float b1[16];
    __shared__ __align__(16) float w2L[16 * 16 * DIN];  // [k][ch][i]
    __shared__ __align__(16) float b2L[16 * DIN];       // [ch][i]
    __shared__ __align__(16) float rootL[DIN * 16];     // [i][ch]
    __shared__ __align__(16) float biasL[16];
    __shared__ __align__(16) float w1m[256];
    __shared__ __align__(16) float b1m[16];
    __shared__ __align__(16) float w2m[16];
    __shared__ float b2m;

    int tid = threadIdx.x;
    if (tid < 64) w1[tid] = eW1[tid];
    if (tid < 16) { b1[tid] = eb1[tid]; biasL[tid] = bias[tid]; }
    // transpose eW2 [k][i*16+ch] -> w2L[(k*16+ch)*DIN+i]
    for (int t = tid; t < 16 * DIN * 16; t += 256) {
        int k = t / (DIN * 16);
        int rem = t - k * DIN * 16;
        int i = rem >> 4;
        int ch = rem & 15;
        w2L[(k * 16 + ch) * DIN + i] = eW2[t];
    }
    for (int t = tid; t < DIN * 16; t += 256) {
        int i = t >> 4, ch = t & 15;
        b2L[ch * DIN + i] = eb2[t];
    }
    for (int t = tid; t < DIN * 16; t += 256) rootL[t] = root[t];
    if constexpr (FINAL) {
        if (tid < 256) w1m[tid] = mW1[tid];
        if (tid < 16) { b1m[tid] = mb1[tid]; w2m[tid] = mW2[tid]; }
        if (tid == 0) b2m = mb2[0];
    }
    __syncthreads();

    int ch = tid & 15;
    int n  = blockIdx.x * 16 + (tid >> 4);     // NN == 3125*16 exactly
    int cnt = cnt_i[n];
    int deg = min(cnt, CAP);
    const int* myl = elist + (size_t)n * CAP;

    float acc = 0.f;
    for (int j = 0; j < deg; ++j) {
        int eid = myl[j];                       // group-uniform broadcast read
        int src = ei[eid];
        float4 a = ((const float4*)ea)[eid];
        // h for this lane's k==ch (shared to group via shfl below)
        float pp = b1[ch] + a.x * w1[ch] + a.y * w1[16 + ch]
                 + a.z * w1[32 + ch] + a.w * w1[48 + ch];
        float h = pp * sigm(pp);
        // source features (same line for all 16 lanes of the group)
        float4 xs4[DIN / 4];
#pragma unroll
        for (int i4 = 0; i4 < DIN / 4; ++i4)
            xs4[i4] = ((const float4*)(xin + (size_t)src * DIN))[i4];
        // bias-of-Wedge term
        float m = 0.f;
        {
            const float4* bp = (const float4*)(b2L + ch * DIN);
#pragma unroll
            for (int i4 = 0; i4 < DIN / 4; ++i4) {
                float4 b = bp[i4];
                m += xs4[i4].x * b.x + xs4[i4].y * b.y + xs4[i4].z * b.z + xs4[i4].w * b.w;
            }
        }
        // m += sum_k h[k] * (xs . w2[k][:,ch])
#pragma unroll
        for (int k = 0; k < 16; ++k) {
            const float4* wp = (const float4*)(w2L + (k * 16 + ch) * DIN);
            float t = 0.f;
#pragma unroll
            for (int i4 = 0; i4 < DIN / 4; ++i4) {
                float4 w = wp[i4];
                t += xs4[i4].x * w.x + xs4[i4].y * w.y + xs4[i4].z * w.z + xs4[i4].w * w.w;
            }
            float hk = __shfl(h, k, 16);       // all 16 group lanes active together
            m += hk * t;
        }
        acc += m;
    }

    // node update: relu(mean + bias + x[n] @ root)
    float v = acc / fmaxf((float)cnt, 1.0f) + biasL[ch];
#pragma unroll
    for (int i = 0; i < DIN; ++i)
        v += xin[(size_t)n * DIN + i] * rootL[i * 16 + ch];
    v = fmaxf(v, 0.f);

    if constexpr (!FINAL) {
        xout[(size_t)n * 16 + ch] = v;
    } else {
        // z[ch] = mb1[ch] + sum_o v[o]*mW1[o][ch]  (cross-lane via shfl)
        float z = b1m[ch];
#pragma unroll
        for (int o = 0; o < 16; ++o) {
            float vo = __shfl(v, o, 16);
            z += vo * w1m[o * 16 + ch];
        }
        float s = z * sigm(z) * w2m[ch];
#pragma unroll
        for (int off = 8; off; off >>= 1) s += __shfl_xor(s, off, 16);
        if (ch == 0) xout[n] = sigm(s + b2m);
    }
}

// ---------------------------------------------------------------------------
// Host launch
// ---------------------------------------------------------------------------
extern "C" void kernel_launch(void* const* d_in, const int* in_sizes, int n_in,
                              void* d_out, int out_size, void* d_ws, size_t ws_size,
                              hipStream_t stream) {
    const float* x     = (const float*)d_in[0];
    const int*   ei    = (const int*)  d_in[1];
    const float* ea    = (const float*)d_in[2];
    const float* eW1_0 = (const float*)d_in[3];
    const float* eb1_0 = (const float*)d_in[4];
    const float* eW2_0 = (const float*)d_in[5];
    const float* eb2_0 = (const float*)d_in[6];
    const float* root0 = (const float*)d_in[7];
    const float* bias0 = (const float*)d_in[8];
    const float* eW1_1 = (const float*)d_in[9];
    const float* eb1_1 = (const float*)d_in[10];
    const float* eW2_1 = (const float*)d_in[11];
    const float* eb2_1 = (const float*)d_in[12];
    const float* root1 = (const float*)d_in[13];
    const float* bias1 = (const float*)d_in[14];
    const float* mW1   = (const float*)d_in[15];
    const float* mb1   = (const float*)d_in[16];
    const float* mW2   = (const float*)d_in[17];
    const float* mb2   = (const float*)d_in[18];
    float* out = (float*)d_out;

    int*   cnt_i = (int*)d_ws;                       // [NN]
    int*   elist = cnt_i + NN;                       // [NN*CAP] = 4.8M ints
    float* x1    = (float*)(elist + (size_t)NN * CAP); // [NN*16]
    // total ws use: (50000 + 4800000 + 800000) * 4 B = 22.6 MB

    hipMemsetAsync(cnt_i, 0, NN * sizeof(int), stream);

    const int EG = NE / 256;   // 3125 exact
    const int GG = NN / 16;    // 3125 exact

    build_buckets<<<EG, 256, 0, stream>>>(ei, cnt_i, elist);

    node_gather<8, false><<<GG, 256, 0, stream>>>(
        ei, ea, eW1_0, eb1_0, eW2_0, eb2_0, root0, bias0, x,
        cnt_i, elist, mW1, mb1, mW2, mb2, x1);

    node_gather<16, true><<<GG, 256, 0, stream>>>(
        ei, ea, eW1_1, eb1_1, eW2_1, eb2_1, root1, bias1, x1,
        cnt_i, elist, mW1, mb1, mW2, mb2, out);
}

// Round 5
// 461.789 us; speedup vs baseline: 3.6773x; 2.0017x over previous
//
#include <hip/hip_runtime.h>

#define NN 50000
#define NE 800000

__device__ __forceinline__ float sigm(float v) { return 1.0f / (1.0f + __expf(-v)); }

// ---------------------------------------------------------------------------
// rank[e] = arrival index of edge e within its dst bucket; cnt_i[d] = degree.
// Int atomics only (~40us at R4's measured rate). Graph is static: runs once,
// reused by both layers.
// ---------------------------------------------------------------------------
__global__ void build_rank(const int* __restrict__ ei,
                           int* __restrict__ cnt_i,
                           int* __restrict__ rank)
{
    int e = blockIdx.x * 256 + threadIdx.x;     // NE == 3125*256 exactly
    rank[e] = atomicAdd(cnt_i + ei[NE + e], 1);
}

// ---------------------------------------------------------------------------
// Exclusive scan of cnt_i -> offset[0..NN]. Single block, 256 threads,
// contiguous 196-element chunks; serial 256-scan by thread 0 (sub-us).
// ---------------------------------------------------------------------------
__global__ void scan_offsets(const int* __restrict__ cnt_i,
                             int* __restrict__ offset)
{
    __shared__ int sums[257];
    int t = threadIdx.x;
    int lo = t * 196, hi = min(lo + 196, NN);
    int s = 0;
    for (int i = lo; i < hi; ++i) s += cnt_i[i];
    sums[t] = s;
    __syncthreads();
    if (t == 0) {
        int run = 0;
        for (int i = 0; i < 256; ++i) { int v = sums[i]; sums[i] = run; run += v; }
        sums[256] = run;
    }
    __syncthreads();
    int run = sums[t];
    for (int i = lo; i < hi; ++i) { offset[i] = run; run += cnt_i[i]; }
    if (t == 255) offset[NN] = sums[256];
}

// ---------------------------------------------------------------------------
// Edge compute (R2 structure: thread-per-edge, LDS weights with WAVE-UNIFORM
// broadcast reads -> ~1 LDS instr per 64 edges, conflict-free).
// msg row written as 4x float4 plain stores to the dst-sorted slot
// msgbuf[offset[dst]+rank[e]] -- no atomics, no RMW.
// ---------------------------------------------------------------------------
template<int DIN>
__global__ __launch_bounds__(256) void edge_compute(
        const int*   __restrict__ ei,
        const float* __restrict__ ea,     // [NE][4]
        const float* __restrict__ eW1,    // [4][16]
        const float* __restrict__ eb1,    // [16]
        const float* __restrict__ eW2,    // [16][DIN*16]
        const float* __restrict__ eb2,    // [DIN*16]
        const float* __restrict__ xin,    // [NN][DIN]
        const int*   __restrict__ offset, // [NN+1]
        const int*   __restrict__ rank,   // [NE]
        float*       __restrict__ msgbuf) // [NE][16]
{
    __shared__ __align__(16) float w1[64];
    __shared__ __align__(16) float b1[16];
    __shared__ __align__(16) float w2[16 * DIN * 16];
    __shared__ __align__(16) float b2[DIN * 16];
    int tid = threadIdx.x;
    if (tid < 64) w1[tid] = eW1[tid];
    if (tid < 16) b1[tid] = eb1[tid];
    for (int i = tid; i < 16 * DIN * 16; i += 256) w2[i] = eW2[i];
    for (int i = tid; i < DIN * 16; i += 256) b2[i] = eb2[i];
    __syncthreads();

    int e = blockIdx.x * 256 + tid;
    int src = ei[e];
    int dst = ei[NE + e];
    int pos = offset[dst] + rank[e];
    float4 a = ((const float4*)ea)[e];

    float h[16];
#pragma unroll
    for (int j = 0; j < 16; ++j) {
        float p = b1[j] + a.x * w1[j] + a.y * w1[16 + j] + a.z * w1[32 + j] + a.w * w1[48 + j];
        h[j] = p * sigm(p);
    }

    float xs[DIN];
#pragma unroll
    for (int i4 = 0; i4 < DIN / 4; ++i4)
        ((float4*)xs)[i4] = ((const float4*)(xin + (size_t)src * DIN))[i4];

    float4* mrow = (float4*)(msgbuf + (size_t)pos * 16);
#pragma unroll 1
    for (int ob = 0; ob < 4; ++ob) {
        float4 acc = make_float4(0.f, 0.f, 0.f, 0.f);
#pragma unroll
        for (int i = 0; i < DIN; ++i) {
            float4 w = *((const float4*)(b2 + i * 16) + ob);   // wave-uniform
#pragma unroll
            for (int k = 0; k < 16; ++k) {
                float4 g = *((const float4*)(w2 + (k * DIN + i) * 16) + ob);  // wave-uniform
                w.x += h[k] * g.x; w.y += h[k] * g.y;
                w.z += h[k] * g.z; w.w += h[k] * g.w;
            }
            acc.x += xs[i] * w.x; acc.y += xs[i] * w.y;
            acc.z += xs[i] * w.z; acc.w += xs[i] * w.w;
        }
        mrow[ob] = acc;
    }
}

// ---------------------------------------------------------------------------
// Gather: 16-lane group per node sums its contiguous msg rows (coalesced,
// no LDS in the loop, no atomics), then fused node update (+ output MLP).
// ---------------------------------------------------------------------------
template<int DIN, bool FINAL>
__global__ __launch_bounds__(256) void gather_nodes(
        const float* __restrict__ xin,    // [NN][DIN]
        const float* __restrict__ root,   // [DIN][16]
        const float* __restrict__ bias,   // [16]
        const int*   __restrict__ offset, // [NN+1]
        const float* __restrict__ msgbuf, // [NE][16]
        const float* __restrict__ mW1,    // [16][16] (FINAL)
        const float* __restrict__ mb1,    // [16]
        const float* __restrict__ mW2,    // [16]
        const float* __restrict__ mb2,    // [1]
        float* __restrict__ xout)         // [NN][16] or [NN]
{
    __shared__ __align__(16) float rootL[DIN * 16];
    __shared__ __align__(16) float biasL[16];
    __shared__ __align__(16) float w1m[256];
    __shared__ __align__(16) float b1m[16];
    __shared__ __align__(16) float w2m[16];
    __shared__ float b2m;
    int tid = threadIdx.x;
    for (int i = tid; i < DIN * 16; i += 256) rootL[i] = root[i];
    if (tid < 16) biasL[tid] = bias[tid];
    if constexpr (FINAL) {
        w1m[tid] = mW1[tid];
        if (tid < 16) { b1m[tid] = mb1[tid]; w2m[tid] = mW2[tid]; }
        if (tid == 0) b2m = mb2[0];
    }
    __syncthreads();

    int ch = tid & 15;
    int n  = blockIdx.x * 16 + (tid >> 4);   // NN == 3125*16 exactly
    int s  = offset[n];
    int epos = offset[n + 1];
    int deg = epos - s;

    float acc = 0.f;
    for (int j = s; j < epos; ++j)
        acc += msgbuf[(size_t)j * 16 + ch];   // 64 lanes -> 4 contiguous rows

    float v = acc / fmaxf((float)deg, 1.0f) + biasL[ch];
#pragma unroll
    for (int i = 0; i < DIN; ++i)
        v += xin[(size_t)n * DIN + i] * rootL[i * 16 + ch];
    v = fmaxf(v, 0.f);

    if constexpr (!FINAL) {
        xout[(size_t)n * 16 + ch] = v;
    } else {
        float z = b1m[ch];
#pragma unroll
        for (int o = 0; o < 16; ++o) {
            float vo = __shfl(v, o, 16);
            z += vo * w1m[o * 16 + ch];
        }
        float ss = z * sigm(z) * w2m[ch];
#pragma unroll
        for (int off = 8; off; off >>= 1) ss += __shfl_xor(ss, off, 16);
        if (ch == 0) xout[n] = sigm(ss + b2m);
    }
}

// ---------------------------------------------------------------------------
// Host launch
// ---------------------------------------------------------------------------
extern "C" void kernel_launch(void* const* d_in, const int* in_sizes, int n_in,
                              void* d_out, int out_size, void* d_ws, size_t ws_size,
                              hipStream_t stream) {
    const float* x     = (const float*)d_in[0];
    const int*   ei    = (const int*)  d_in[1];
    const float* ea    = (const float*)d_in[2];
    const float* eW1_0 = (const float*)d_in[3];
    const float* eb1_0 = (const float*)d_in[4];
    const float* eW2_0 = (const float*)d_in[5];
    const float* eb2_0 = (const float*)d_in[6];
    const float* root0 = (const float*)d_in[7];
    const float* bias0 = (const float*)d_in[8];
    const float* eW1_1 = (const float*)d_in[9];
    const float* eb1_1 = (const float*)d_in[10];
    const float* eW2_1 = (const float*)d_in[11];
    const float* eb2_1 = (const float*)d_in[12];
    const float* root1 = (const float*)d_in[13];
    const float* bias1 = (const float*)d_in[14];
    const float* mW1   = (const float*)d_in[15];
    const float* mb1   = (const float*)d_in[16];
    const float* mW2   = (const float*)d_in[17];
    const float* mb2   = (const float*)d_in[18];
    float* out = (float*)d_out;

    // ws layout (floats/ints, msgbuf 16B-aligned):
    int*   cnt_i  = (int*)d_ws;                    // [0, 50000)
    int*   offset = cnt_i + NN;                    // [50000, 100001)
    int*   rank   = (int*)d_ws + 100004;           // [100004, 900004)
    float* msgbuf = (float*)d_ws + 900004;         // [900004, 13700004) = [NE][16]
    float* x1     = (float*)d_ws + 13700004;       // [13700004, 14500004)
    // total: 58.0 MB (fits: useG path proved ws >= 61 MB in R1)

    hipMemsetAsync(cnt_i, 0, NN * sizeof(int), stream);

    const int EG = NE / 256;   // 3125
    const int GG = NN / 16;    // 3125

    build_rank<<<EG, 256, 0, stream>>>(ei, cnt_i, rank);
    scan_offsets<<<1, 256, 0, stream>>>(cnt_i, offset);

    // ---- layer 0 ----
    edge_compute<8><<<EG, 256, 0, stream>>>(ei, ea, eW1_0, eb1_0, eW2_0, eb2_0,
                                            x, offset, rank, msgbuf);
    gather_nodes<8, false><<<GG, 256, 0, stream>>>(x, root0, bias0, offset, msgbuf,
                                                   mW1, mb1, mW2, mb2, x1);

    // ---- layer 1 ----
    edge_compute<16><<<EG, 256, 0, stream>>>(ei, ea, eW1_1, eb1_1, eW2_1, eb2_1,
                                             x1, offset, rank, msgbuf);
    gather_nodes<16, true><<<GG, 256, 0, stream>>>(x1, root1, bias1, offset, msgbuf,
                                                   mW1, mb1, mW2, mb2, out);
}